// Round 2
// 596.650 us; speedup vs baseline: 1.0276x; 1.0276x over previous
//
#include <hip/hip_runtime.h>

#define N_NODES 50000
#define N_EDGES 800000
#define EMB 96
#define HID 192

#define HIST_BLOCKS ((N_EDGES + 255) / 256)        // 3125
#define CONV_BLOCKS ((2 * EMB * HID + 255) / 256)  // 144

typedef __attribute__((ext_vector_type(8))) short short8;
typedef __attribute__((ext_vector_type(4))) float f32x4;
typedef __attribute__((ext_vector_type(4))) unsigned short ushort4v;

static __device__ __forceinline__ unsigned short f2bf(float f) {
    union { float f; unsigned int u; } v; v.f = f;
    unsigned int u = v.u;
    return (unsigned short)((u + 0x7FFFu + ((u >> 16) & 1u)) >> 16);
}

// ---- fused: histogram of dst (blocks [0, HIST_BLOCKS)) + weight transpose->bf16
__global__ __launch_bounds__(256) void hist_conv_kernel(
    const int* __restrict__ dst, int* __restrict__ counts,
    const float* __restrict__ W1, const float* __restrict__ W2,
    unsigned short* __restrict__ W1t, unsigned short* __restrict__ W2t)
{
    int b = blockIdx.x;
    if (b < HIST_BLOCKS) {
        int e = b * 256 + threadIdx.x;
        if (e < N_EDGES) atomicAdd(&counts[dst[e]], 1);
    } else {
        int i = (b - HIST_BLOCKS) * 256 + threadIdx.x;
        if (i < EMB * HID) {                 // W1t: [HID][EMB]
            int n = i / EMB, k = i % EMB;
            W1t[i] = f2bf(W1[(size_t)k * HID + n]);
        } else if (i < 2 * EMB * HID) {      // W2t: [EMB][HID]
            int j = i - EMB * HID;
            int n = j / HID, k = j % HID;
            W2t[j] = f2bf(W2[(size_t)k * EMB + n]);
        }
    }
}

// ---- exclusive scan of counts (single workgroup, 1024 thr, prefetched tiles)
__global__ __launch_bounds__(1024) void scan_kernel(
    const int* __restrict__ counts, int* __restrict__ offsets)
{
    __shared__ int wave_sums[16];
    int t = threadIdx.x;
    int lane = t & 63, wave = t >> 6;
    int running = 0;
    int v_next = (t < N_NODES) ? counts[t] : 0;   // prefetch tile 0
    for (int base = 0; base < N_NODES; base += 1024) {
        int v = v_next;
        int nidx = base + 1024 + t;
        v_next = (nidx < N_NODES) ? counts[nidx] : 0;   // prefetch next tile early
        int x = v;
        #pragma unroll
        for (int d = 1; d < 64; d <<= 1) {
            int y = __shfl_up(x, d);
            if (lane >= d) x += y;
        }
        if (lane == 63) wave_sums[wave] = x;
        __syncthreads();
        if (t < 16) {
            int s = wave_sums[t];
            #pragma unroll
            for (int d = 1; d < 16; d <<= 1) {
                int y = __shfl_up(s, d);
                if (t >= d) s += y;
            }
            wave_sums[t] = s;
        }
        __syncthreads();
        int woff = wave ? wave_sums[wave - 1] : 0;
        if (base + t < N_NODES) offsets[base + t] = running + woff + x - v;
        int total = wave_sums[15];
        __syncthreads();
        running += total;
    }
    if (t == 0) offsets[N_NODES] = running;
}

// ---- fill CSR buckets with (edge_id, src) pairs
__global__ __launch_bounds__(256) void fill_kernel(
    const int* __restrict__ src, const int* __restrict__ dst,
    const int* __restrict__ offsets, int* __restrict__ cursor,
    int2* __restrict__ pairs)
{
    int e = blockIdx.x * 256 + threadIdx.x;
    if (e < N_EDGES) {
        int d = dst[e];
        int pos = offsets[d] + atomicAdd(&cursor[d], 1);
        pairs[pos] = make_int2(e, src[e]);
    }
}

// ---- gather-reduce, 24 lanes/node, 4-edge unroll (8 loads in flight)
// ea is streamed once -> nontemporal so h/pairs stay cache-resident.
__global__ __launch_bounds__(192) void gather_kernel4(
    const f32x4* __restrict__ h4, const f32x4* __restrict__ ea4,
    const int* __restrict__ offsets, const int2* __restrict__ pairs,
    unsigned short* __restrict__ aggr_bf)
{
    int n = blockIdx.x * 8 + threadIdx.x / 24;
    int c = threadIdx.x % 24;
    if (n >= N_NODES) return;
    int beg = offsets[n], end = offsets[n + 1];
    f32x4 a0 = {0.f, 0.f, 0.f, 0.f}, a1 = a0, a2 = a0, a3 = a0;
    int i = beg;
    for (; i + 4 <= end; i += 4) {
        int2 q0 = pairs[i], q1 = pairs[i + 1], q2 = pairs[i + 2], q3 = pairs[i + 3];
        f32x4 e0 = __builtin_nontemporal_load(&ea4[(size_t)q0.x * 24 + c]);
        f32x4 e1 = __builtin_nontemporal_load(&ea4[(size_t)q1.x * 24 + c]);
        f32x4 e2 = __builtin_nontemporal_load(&ea4[(size_t)q2.x * 24 + c]);
        f32x4 e3 = __builtin_nontemporal_load(&ea4[(size_t)q3.x * 24 + c]);
        f32x4 g0 = h4[(size_t)q0.y * 24 + c];
        f32x4 g1 = h4[(size_t)q1.y * 24 + c];
        f32x4 g2 = h4[(size_t)q2.y * 24 + c];
        f32x4 g3 = h4[(size_t)q3.y * 24 + c];
        a0 += e0 + g0;
        a1 += e1 + g1;
        a2 += e2 + g2;
        a3 += e3 + g3;
    }
    for (; i < end; ++i) {
        int2 q = pairs[i];
        f32x4 e = __builtin_nontemporal_load(&ea4[(size_t)q.x * 24 + c]);
        f32x4 g = h4[(size_t)q.y * 24 + c];
        a0 += e + g;
    }
    f32x4 acc = (a0 + a1) + (a2 + a3);
    ushort4v o;
    o.x = f2bf(acc.x); o.y = f2bf(acc.y); o.z = f2bf(acc.z); o.w = f2bf(acc.w);
    *(ushort4v*)(aggr_bf + (size_t)n * EMB + c * 4) = o;
}

// ---- fused MLP: out = (1+eps)*h + relu(aggr @ W1 + b1) @ W2 + b2
// W1 staged in LDS [192][pad 104]; after layer-1 barrier the same LDS region is
// reused for per-wave hidden tiles [16][pad 200]. W2 B-frags read from global
// (36.9 KB table, L1/L2-resident, identical addresses across waves).
__global__ __launch_bounds__(256) void mlp_fused(
    const unsigned short* __restrict__ aggr_bf,
    const unsigned short* __restrict__ W1t, const float* __restrict__ b1,
    const unsigned short* __restrict__ W2t, const float* __restrict__ b2,
    const float* __restrict__ h, const float* __restrict__ eps,
    float* __restrict__ out)
{
    __shared__ unsigned short sW1[HID * 104];   // 39936 B; reused for hidden tiles
    int t = threadIdx.x;
    const unsigned int* p1 = (const unsigned int*)W1t;
    for (int i = t; i < HID * (EMB / 2); i += 256) {
        int n = i / (EMB / 2), c2 = i % (EMB / 2);
        *(unsigned int*)&sW1[n * 104 + c2 * 2] = p1[(size_t)n * (EMB / 2) + c2];
    }
    __syncthreads();

    int wave = t >> 6, lane = t & 63;
    int m0 = (blockIdx.x * 4 + wave) * 16;
    bool active = (m0 < N_NODES);               // do NOT return: barriers below
    int quad = lane >> 4, col = lane & 15;
    int m = m0 + col;

    // ---- layer 1: 16x192 hidden per wave
    f32x4 acc1[12];
    #pragma unroll
    for (int c = 0; c < 12; ++c) acc1[c] = (f32x4){0.f, 0.f, 0.f, 0.f};
    if (active) {
        #pragma unroll
        for (int ks = 0; ks < 3; ++ks) {
            short8 af = *(const short8*)(aggr_bf + (size_t)m * EMB + ks * 32 + quad * 8);
            #pragma unroll
            for (int c = 0; c < 12; ++c) {
                short8 bf = *(const short8*)(sW1 + (c * 16 + col) * 104 + ks * 32 + quad * 8);
                acc1[c] = __builtin_amdgcn_mfma_f32_16x16x32_bf16(af, bf, acc1[c], 0, 0, 0);
            }
        }
    }
    __syncthreads();   // all waves done reading W1 -> region reusable

    if (active) {
        // bias + relu + bf16, into this wave's private hidden tile [16][200]
        unsigned short* sH = sW1 + wave * (16 * 200);
        #pragma unroll
        for (int c = 0; c < 12; ++c) {
            float bias = b1[c * 16 + col];
            #pragma unroll
            for (int r = 0; r < 4; ++r) {
                int lr = quad * 4 + r;
                sH[lr * 200 + c * 16 + col] = f2bf(fmaxf(acc1[c][r] + bias, 0.f));
            }
        }
        // ---- layer 2: A from own LDS tile, B straight from global W2t
        f32x4 acc2[6];
        #pragma unroll
        for (int c = 0; c < 6; ++c) acc2[c] = (f32x4){0.f, 0.f, 0.f, 0.f};
        #pragma unroll
        for (int ks = 0; ks < 6; ++ks) {
            short8 af = *(const short8*)(sH + col * 200 + ks * 32 + quad * 8);
            #pragma unroll
            for (int c = 0; c < 6; ++c) {
                short8 bf = *(const short8*)(W2t + (size_t)(c * 16 + col) * HID + ks * 32 + quad * 8);
                acc2[c] = __builtin_amdgcn_mfma_f32_16x16x32_bf16(af, bf, acc2[c], 0, 0, 0);
            }
        }
        float s = 1.f + eps[0];
        #pragma unroll
        for (int c = 0; c < 6; ++c) {
            float bias = b2[c * 16 + col];
            #pragma unroll
            for (int r = 0; r < 4; ++r) {
                int row = m0 + quad * 4 + r;
                size_t idx = (size_t)row * EMB + c * 16 + col;
                out[idx] = acc2[c][r] + bias + s * h[idx];
            }
        }
    }
}

extern "C" void kernel_launch(void* const* d_in, const int* in_sizes, int n_in,
                              void* d_out, int out_size, void* d_ws, size_t ws_size,
                              hipStream_t stream) {
    const float* h         = (const float*)d_in[0];
    const float* edge_attr = (const float*)d_in[1];
    const int*   src       = (const int*)d_in[2];
    const int*   dst       = (const int*)d_in[3];
    const float* W1        = (const float*)d_in[4];
    const float* b1        = (const float*)d_in[5];
    const float* W2        = (const float*)d_in[6];
    const float* b2        = (const float*)d_in[7];
    const float* eps       = (const float*)d_in[8];
    float* out = (float*)d_out;

    unsigned char* wsp = (unsigned char*)d_ws;
    unsigned short* aggr_bf = (unsigned short*)wsp; wsp += (size_t)N_NODES * EMB * 2;
    unsigned short* W1t     = (unsigned short*)wsp; wsp += (size_t)EMB * HID * 2;
    unsigned short* W2t     = (unsigned short*)wsp; wsp += (size_t)EMB * HID * 2;
    int2* pairs   = (int2*)wsp; wsp += (size_t)N_EDGES * sizeof(int2);
    int*  offsets = (int*)wsp;  wsp += (size_t)(N_NODES + 1) * sizeof(int);
    int*  counts  = (int*)wsp;  wsp += (size_t)N_NODES * sizeof(int);
    int*  cursor  = (int*)wsp;

    hipMemsetAsync(counts, 0, (size_t)2 * N_NODES * sizeof(int), stream);

    hist_conv_kernel<<<HIST_BLOCKS + CONV_BLOCKS, 256, 0, stream>>>(
        dst, counts, W1, W2, W1t, W2t);
    scan_kernel<<<1, 1024, 0, stream>>>(counts, offsets);
    fill_kernel<<<(N_EDGES + 255) / 256, 256, 0, stream>>>(src, dst, offsets, cursor, pairs);
    gather_kernel4<<<(N_NODES + 7) / 8, 192, 0, stream>>>(
        (const f32x4*)h, (const f32x4*)edge_attr, offsets, pairs, aggr_bf);
    mlp_fused<<<(N_NODES / 16 + 3) / 4, 256, 0, stream>>>(
        aggr_bf, W1t, b1, W2t, b2, h, eps, out);
}